// Round 14
// baseline (497.194 us; speedup 1.0000x reference)
//
#include <hip/hip_runtime.h>
#include <hip/hip_bf16.h>
#include <math.h>

#define B_SZ 128
#define N_OTH 2048
#define F_IMG 1024
#define F_TXT 512
#define D_EMB 512
#define TOT (B_SZ * N_OTH)

typedef __attribute__((ext_vector_type(8))) short short8;    // 8 bf16 (4 VGPR)
typedef __attribute__((ext_vector_type(16))) float f32x16;   // 32x32 MFMA acc

static __device__ __forceinline__ ushort f2bf(float f) {
    __hip_bfloat16 h = __float2bfloat16(f);   // HW RNE convert
    return *reinterpret_cast<ushort*>(&h);
}

static __device__ __forceinline__ void glds16(const float* g, float* l) {
    __builtin_amdgcn_global_load_lds((const __attribute__((address_space(1))) void*)g,
                                     (__attribute__((address_space(3))) void*)l, 16, 0, 0);
}

// ---------------- fused: encoders (blocks 0..127) + W-prep (blocks 128..191) ----------------
__global__ __launch_bounds__(512) void k_prep(const float* __restrict__ in_img,
                                              const float* __restrict__ in_txt,
                                              const float* __restrict__ W_img,
                                              const float* __restrict__ W_txt,
                                              const float* __restrict__ p_ls,
                                              float* __restrict__ img,
                                              float* __restrict__ logit_in,
                                              ushort* __restrict__ wf) {
    if (blockIdx.x >= B_SZ) {
        // W_txt -> bf16 32x32x16-MFMA B-fragment repack:
        // frag = kstep(0..31)*16 + ct(0..15); lane l: col ct*32+(l&31), k = kstep*16+(l>>5)*8+j
        const int g = (blockIdx.x - B_SZ) * 512 + threadIdx.x;   // 32768 total
        const int l = g & 63;
        const int frag = g >> 6;
        const int kstep = frag >> 4;
        const int ct = frag & 15;
        const int col = ct * 32 + (l & 31);
        const int kb = kstep * 16 + (l >> 5) * 8;
        short8 o;
#pragma unroll
        for (int j = 0; j < 8; ++j) o[j] = (short)f2bf(W_txt[(kb + j) * D_EMB + col]);
        *(short8*)(wf + (size_t)g * 8) = o;
        return;
    }
    const int b = blockIdx.x;
    const int d = threadIdx.x;
    __shared__ float row[F_IMG];
    __shared__ float wsum[8];
    __shared__ float s_rn;
    const int lane = d & 63, wv = d >> 6;

    for (int i = d; i < F_IMG; i += 512) row[i] = in_img[b * F_IMG + i];
    __syncthreads();
    float acc = 0.f;
#pragma unroll 8
    for (int f = 0; f < F_IMG; ++f) acc = fmaf(row[f], W_img[f * D_EMB + d], acc);
    float sq = acc * acc;
#pragma unroll
    for (int off = 32; off > 0; off >>= 1) sq += __shfl_down(sq, off);
    if (lane == 0) wsum[wv] = sq;
    __syncthreads();
    if (d == 0) {
        float s = 0.f;
        for (int w = 0; w < 8; ++w) s += wsum[w];
        s_rn = 1.0f / sqrtf(s);
    }
    __syncthreads();
    const float iv = acc * s_rn;
    img[b * D_EMB + d] = iv;

    __syncthreads();
    row[d] = in_txt[b * F_TXT + d];
    __syncthreads();
    float tacc = 0.f;
#pragma unroll 8
    for (int f = 0; f < F_TXT; ++f) tacc = fmaf(row[f], W_txt[f * D_EMB + d], tacc);
    float tsq = tacc * tacc;
#pragma unroll
    for (int off = 32; off > 0; off >>= 1) tsq += __shfl_down(tsq, off);
    __syncthreads();
    if (lane == 0) wsum[wv] = tsq;
    __syncthreads();
    if (d == 0) {
        float s = 0.f;
        for (int w = 0; w < 8; ++w) s += wsum[w];
        s_rn = 1.0f / sqrtf(s);
    }
    __syncthreads();
    float pd = (tacc * s_rn) * iv;
#pragma unroll
    for (int off = 32; off > 0; off >>= 1) pd += __shfl_down(pd, off);
    __syncthreads();
    if (lane == 0) wsum[wv] = pd;
    __syncthreads();
    if (d == 0) {
        float s = 0.f;
        for (int w = 0; w < 8; ++w) s += wsum[w];
        logit_in[b] = expf(p_ls[0]) * s;
    }
}

// ---------------- fused GEMM + num/den partial reduction ----------------
// Grid: strip(4096) x h(2); consecutive blockIdx = the two halves of a strip
// (co-dispatched -> A rows served by L3/L2 for the second reader).
// Block: 256 thr = 4 waves, BM=64 rows x BN=256 cols, BK=64, K=512 (8 tiles).
// Wave wv: 64 rows x cols [h*256 + wv*64, +64). acc = 2m x 2n x f32x16 = 64 AGPR.
// A: fp32 via global_load_lds (zero staging VGPRs), 2 LDS buffers, 16-chunk XOR
//    swizzle done on the GLOBAL SOURCE (linear LDS dest) + same XOR on ds_read.
//    bf16 convert at fragment-read time.
// Loop = minimal 2-phase: {glds(t+1) -> B(t) regs -> ds_read+cvt+MFMA -> __syncthreads}.
// __launch_bounds__(256,4): force unified VGPR+AGPR <= 128 -> 4 blocks/CU target.
__global__ __launch_bounds__(256, 4) void k_gemm(const float* __restrict__ oth,
                                                 const ushort* __restrict__ wf,
                                                 const float* __restrict__ img,
                                                 float* __restrict__ numA,    // [2][TOT]
                                                 float* __restrict__ denA) {  // [2][TOT]
    __shared__ float sA[2][64 * 64];   // 2 x 16 KB fp32
    __shared__ float redN[4][64];
    __shared__ float redD[4][64];
    const int tid = threadIdx.x;
    const int l = tid & 63;
    const int wv = tid >> 6;
    const int strip = blockIdx.x >> 1;
    const int h = blockIdx.x & 1;
    const int b = strip >> 5;
    const size_t row0 = (size_t)strip * 64;

    // glds staging: wave wv, instr j covers rows wv*16+j*4 + (l>>4); lane chunk c = l&15.
    // Source chunk = c ^ (row & 15)  ->  LDS[row][c] = G[row][c ^ (row&15)] (16B chunks).
    const float* gsrc[4];
    int ldsoff[4];   // float offset of this wave-instr's 1 KB segment
#pragma unroll
    for (int j = 0; j < 4; ++j) {
        const int r0 = wv * 16 + j * 4 + (l >> 4);
        const int c = l & 15;
        gsrc[j] = oth + (row0 + r0) * F_TXT + (size_t)((c ^ (r0 & 15)) * 4);
        ldsoff[j] = (wv * 4 + j) * 256;
    }

    // B fragments: ct = h*8 + wv*2 + n; frag = (t*4+ks)*16 + ct; addr = (frag*64+l)*8
    const ushort* wbase = wf + ((size_t)(h * 8 + wv * 2) * 64 + l) * 8;

    // A-read: row r = m*32 + (l&31), rbase = r*256 bytes; chunk g0 = ks*4 + (l>>5)*2;
    // byte = rbase + ((g ^ (r&15)) << 4); r&15 == l&15.
    const int rx = l & 15;
    int rbase[2];
#pragma unroll
    for (int m = 0; m < 2; ++m) rbase[m] = (m * 32 + (l & 31)) * 256;

    f32x16 acc[2][2];
#pragma unroll
    for (int m = 0; m < 2; ++m)
#pragma unroll
        for (int n = 0; n < 2; ++n)
#pragma unroll
            for (int r = 0; r < 16; ++r) acc[m][n][r] = 0.f;

    // prologue: stage tile 0 (glds); __syncthreads drains vmcnt(0)
#pragma unroll
    for (int j = 0; j < 4; ++j) glds16(gsrc[j], &sA[0][0] + ldsoff[j]);
    __syncthreads();

#pragma unroll
    for (int t = 0; t < 8; ++t) {
        const int cur = t & 1;
        // stage tile t+1 into the other buffer (lands under this tile's compute;
        // drained by the vmcnt(0) inside the next __syncthreads)
        if (t < 7) {
#pragma unroll
            for (int j = 0; j < 4; ++j)
                glds16(gsrc[j] + (t + 1) * 64, &sA[cur ^ 1][0] + ldsoff[j]);
        }
        // B(t) from L2
        short8 bfr[4][2];
#pragma unroll
        for (int ks = 0; ks < 4; ++ks)
#pragma unroll
            for (int n = 0; n < 2; ++n)
                bfr[ks][n] = *(const short8*)(wbase + (size_t)((t * 4 + ks) * 16 + n) * 512);
        // compute: fp32 ds_read (swizzled) + cvt + MFMA
#pragma unroll
        for (int ks = 0; ks < 4; ++ks) {
            short8 af[2];
#pragma unroll
            for (int m = 0; m < 2; ++m) {
                const int g0 = ks * 4 + (l >> 5) * 2;
                const float4 fa = *(const float4*)((const char*)&sA[cur][0] + rbase[m] + (((g0 + 0) ^ rx) << 4));
                const float4 fb = *(const float4*)((const char*)&sA[cur][0] + rbase[m] + (((g0 + 1) ^ rx) << 4));
                short8 v;
                v[0] = (short)f2bf(fa.x); v[1] = (short)f2bf(fa.y);
                v[2] = (short)f2bf(fa.z); v[3] = (short)f2bf(fa.w);
                v[4] = (short)f2bf(fb.x); v[5] = (short)f2bf(fb.y);
                v[6] = (short)f2bf(fb.z); v[7] = (short)f2bf(fb.w);
                af[m] = v;
            }
#pragma unroll
            for (int m = 0; m < 2; ++m)
#pragma unroll
                for (int n = 0; n < 2; ++n)
                    acc[m][n] = __builtin_amdgcn_mfma_f32_32x32x16_bf16(af[m], bfr[ks][n], acc[m][n], 0, 0, 0);
        }
        __syncthreads();   // vmcnt(0)+lgkmcnt(0): glds(t+1) landed, all waves in step
    }

    // epilogue: per-row partials num = sum_c P*img[c], den = sum_c P^2 (this half)
    float ic[2];
#pragma unroll
    for (int n = 0; n < 2; ++n)
        ic[n] = img[b * D_EMB + h * 256 + wv * 64 + n * 32 + (l & 31)];
#pragma unroll
    for (int m = 0; m < 2; ++m) {
#pragma unroll
        for (int rg = 0; rg < 16; ++rg) {
            const float pv = acc[m][0][rg];
            const float qv = acc[m][1][rg];
            float tn = pv * ic[0] + qv * ic[1];
            float td = pv * pv + qv * qv;
#pragma unroll
            for (int off = 1; off <= 16; off <<= 1) {
                tn += __shfl_xor(tn, off);
                td += __shfl_xor(td, off);
            }
            if ((l & 31) == 0) {
                const int r = m * 32 + (rg & 3) + 8 * (rg >> 2) + 4 * (l >> 5);
                redN[wv][r] = tn;
                redD[wv][r] = td;
            }
        }
    }
    __syncthreads();
    if (tid < 64) {
        float tn = 0.f, td = 0.f;
#pragma unroll
        for (int w = 0; w < 4; ++w) { tn += redN[w][tid]; td += redD[w][tid]; }
        numA[(size_t)h * TOT + row0 + tid] = tn;
        denA[(size_t)h * TOT + row0 + tid] = td;
    }
}

// ---------------- logits + full bitonic sort + output assembly ----------------
__global__ __launch_bounds__(512) void k_topk(const float* __restrict__ numA,
                                              const float* __restrict__ denA,
                                              const float* __restrict__ logit_in,
                                              const float* __restrict__ p_ls,
                                              float* __restrict__ out) {
    const int b = blockIdx.x;
    const int tid = threadIdx.x;
    const float scale = expf(p_ls[0]);
    __shared__ float a[N_OTH];
    for (int i = tid; i < N_OTH; i += 512) {
        const size_t idx = (size_t)b * N_OTH + i;
        const float nu = numA[idx] + numA[TOT + idx];
        const float de = denA[idx] + denA[TOT + idx];
        a[i] = scale * nu / sqrtf(de);
    }
    __syncthreads();
    for (unsigned k = 2; k <= N_OTH; k <<= 1) {
        for (unsigned j = k >> 1; j > 0; j >>= 1) {
#pragma unroll
            for (int s = 0; s < N_OTH / 512; ++s) {
                const unsigned i = tid + s * 512u;
                const unsigned ixj = i ^ j;
                if (ixj > i) {
                    const bool asc = ((i & k) == 0);
                    const float x = a[i], y = a[ixj];
                    if ((x > y) == asc) { a[i] = y; a[ixj] = x; }
                }
            }
            __syncthreads();
        }
    }
    if (tid < 128) {
        const int j = tid;
        float v;
        if (j == b) {
            v = logit_in[b];
        } else {
            const int m = j - (j > b ? 1 : 0);
            v = a[N_OTH - 1 - m];
        }
        out[b * 128 + j] = v;
    }
}

extern "C" void kernel_launch(void* const* d_in, const int* in_sizes, int n_in,
                              void* d_out, int out_size, void* d_ws, size_t ws_size,
                              hipStream_t stream) {
    const float* in_img = (const float*)d_in[0];
    const float* in_txt = (const float*)d_in[1];
    const float* oth    = (const float*)d_in[2];
    const float* W_img  = (const float*)d_in[3];
    const float* W_txt  = (const float*)d_in[4];
    const float* p_ls   = (const float*)d_in[5];
    float* out = (float*)d_out;

    float* ws = (float*)d_ws;
    float* img      = ws;                                   // 65536
    float* logit_in = ws + 65536;                           // 128
    float* numA     = ws + 65536 + 128;                     // 2*TOT
    float* denA     = numA + 2 * TOT;                       // 2*TOT
    ushort* wfrag   = (ushort*)(denA + 2 * TOT);            // 262144 ushorts

    k_prep<<<B_SZ + 64, 512, 0, stream>>>(in_img, in_txt, W_img, W_txt, p_ls, img, logit_in, wfrag);
    k_gemm<<<(TOT / 64) * 2, 256, 0, stream>>>(oth, wfrag, img, numA, denA);
    k_topk<<<B_SZ, 512, 0, stream>>>(numA, denA, logit_in, p_ls, out);
}

// Round 15
// 375.360 us; speedup vs baseline: 1.3246x; 1.3246x over previous
//
#include <hip/hip_runtime.h>
#include <hip/hip_bf16.h>
#include <math.h>

#define B_SZ 128
#define N_OTH 2048
#define F_IMG 1024
#define F_TXT 512
#define D_EMB 512
#define TOT (B_SZ * N_OTH)

typedef __attribute__((ext_vector_type(8))) short short8;    // 8 bf16 (4 VGPR)
typedef __attribute__((ext_vector_type(16))) float f32x16;   // 32x32 MFMA acc

static __device__ __forceinline__ ushort f2bf(float f) {
    __hip_bfloat16 h = __float2bfloat16(f);   // HW RNE convert
    return *reinterpret_cast<ushort*>(&h);
}

// ---------------- fused: encoders (blocks 0..127) + W-prep (blocks 128..191) ----------------
__global__ __launch_bounds__(512) void k_prep(const float* __restrict__ in_img,
                                              const float* __restrict__ in_txt,
                                              const float* __restrict__ W_img,
                                              const float* __restrict__ W_txt,
                                              const float* __restrict__ p_ls,
                                              float* __restrict__ img,
                                              float* __restrict__ logit_in,
                                              ushort* __restrict__ wf) {
    if (blockIdx.x >= B_SZ) {
        // W_txt -> bf16 32x32x16-MFMA B-fragment repack:
        // frag = kstep(0..31)*16 + ct(0..15); lane l: col ct*32+(l&31), k = kstep*16+(l>>5)*8+j
        const int g = (blockIdx.x - B_SZ) * 512 + threadIdx.x;   // 32768 total
        const int l = g & 63;
        const int frag = g >> 6;
        const int kstep = frag >> 4;
        const int ct = frag & 15;
        const int col = ct * 32 + (l & 31);
        const int kb = kstep * 16 + (l >> 5) * 8;
        short8 o;
#pragma unroll
        for (int j = 0; j < 8; ++j) o[j] = (short)f2bf(W_txt[(kb + j) * D_EMB + col]);
        *(short8*)(wf + (size_t)g * 8) = o;
        return;
    }
    const int b = blockIdx.x;
    const int d = threadIdx.x;
    __shared__ float row[F_IMG];
    __shared__ float wsum[8];
    __shared__ float s_rn;
    const int lane = d & 63, wv = d >> 6;

    for (int i = d; i < F_IMG; i += 512) row[i] = in_img[b * F_IMG + i];
    __syncthreads();
    float acc = 0.f;
#pragma unroll 8
    for (int f = 0; f < F_IMG; ++f) acc = fmaf(row[f], W_img[f * D_EMB + d], acc);
    float sq = acc * acc;
#pragma unroll
    for (int off = 32; off > 0; off >>= 1) sq += __shfl_down(sq, off);
    if (lane == 0) wsum[wv] = sq;
    __syncthreads();
    if (d == 0) {
        float s = 0.f;
        for (int w = 0; w < 8; ++w) s += wsum[w];
        s_rn = 1.0f / sqrtf(s);
    }
    __syncthreads();
    const float iv = acc * s_rn;
    img[b * D_EMB + d] = iv;

    __syncthreads();
    row[d] = in_txt[b * F_TXT + d];
    __syncthreads();
    float tacc = 0.f;
#pragma unroll 8
    for (int f = 0; f < F_TXT; ++f) tacc = fmaf(row[f], W_txt[f * D_EMB + d], tacc);
    float tsq = tacc * tacc;
#pragma unroll
    for (int off = 32; off > 0; off >>= 1) tsq += __shfl_down(tsq, off);
    __syncthreads();
    if (lane == 0) wsum[wv] = tsq;
    __syncthreads();
    if (d == 0) {
        float s = 0.f;
        for (int w = 0; w < 8; ++w) s += wsum[w];
        s_rn = 1.0f / sqrtf(s);
    }
    __syncthreads();
    float pd = (tacc * s_rn) * iv;
#pragma unroll
    for (int off = 32; off > 0; off >>= 1) pd += __shfl_down(pd, off);
    __syncthreads();
    if (lane == 0) wsum[wv] = pd;
    __syncthreads();
    if (d == 0) {
        float s = 0.f;
        for (int w = 0; w < 8; ++w) s += wsum[w];
        logit_in[b] = expf(p_ls[0]) * s;
    }
}

// ---------------- fused GEMM + num/den reduction (single-barrier blocks) ----------------
// Grid: 4096 strips. Block: 256 thr = 4 waves, BM=64 rows x full N=512 cols, BK=512
// (entire K in LDS). Wave wv: all 64 rows x cols [wv*128, +128);
// acc = 2m x 4n x f32x16 = 128 regs.
// Phase 1 (no barriers): each thread streams its 128 floats (4 batches x 8 float4),
//   cvt once -> bf16, ds_write_b128 with 16B-granule XOR swizzle (g ^= row&15).
// ONE __syncthreads. Phase 2 (no barriers): 32 k-steps {2 ds_read_b128 + 8 MFMA},
//   B via depth-2 register queue from L2-resident wfrag (static even/odd unroll).
// Two blocks/CU overlap: one streams HBM while the other runs MFMA (m114 mechanism).
__global__ __launch_bounds__(256, 2) void k_gemm(const float* __restrict__ oth,
                                                 const ushort* __restrict__ wf,
                                                 const float* __restrict__ img,
                                                 float* __restrict__ numA,    // [TOT]
                                                 float* __restrict__ denA) {  // [TOT]
    __shared__ ushort sA[64 * 512];   // 64 KB bf16, swizzled 16B granules
    __shared__ float redN[4][64];
    __shared__ float redD[4][64];
    const int tid = threadIdx.x;
    const int l = tid & 63;
    const int wv = tid >> 6;
    const int strip = blockIdx.x;          // 0..4095
    const int b = strip >> 5;
    const size_t row0 = (size_t)strip * 64;

    // ---------- phase 1: stage A (fp32 HBM -> bf16 LDS), no barriers ----------
    const int srow = tid >> 2;             // 0..63
    const int seg = tid & 3;               // 128-float segment within row
    const float* gsrc = oth + (row0 + srow) * F_TXT + seg * 128;
    char* lrow = (char*)sA + srow * 1024;  // 1 KB per row
    const int rsw = srow & 15;             // granule XOR key

#pragma unroll 1
    for (int bt = 0; bt < 4; ++bt) {
        float4 v[8];
#pragma unroll
        for (int i = 0; i < 8; ++i)
            v[i] = *(const float4*)(gsrc + bt * 32 + i * 4);
#pragma unroll
        for (int gi = 0; gi < 4; ++gi) {
            const int g = seg * 16 + bt * 4 + gi;     // granule (8 bf16) within row
            const float4 a = v[gi * 2];
            const float4 c = v[gi * 2 + 1];
            short8 p;
            p[0] = (short)f2bf(a.x); p[1] = (short)f2bf(a.y);
            p[2] = (short)f2bf(a.z); p[3] = (short)f2bf(a.w);
            p[4] = (short)f2bf(c.x); p[5] = (short)f2bf(c.y);
            p[6] = (short)f2bf(c.z); p[7] = (short)f2bf(c.w);
            *(short8*)(lrow + ((g ^ rsw) << 4)) = p;
        }
    }
    __syncthreads();   // THE single barrier

    // ---------- phase 2: 32 k-steps, no barriers ----------
    // A-read: row r = m*32 + (l&31); granule = (ks*2 + (l>>5)) ^ (l&15)
    const int rx = l & 15;
    const int gsel = l >> 5;
    int rbase[2];
#pragma unroll
    for (int m = 0; m < 2; ++m) rbase[m] = (m * 32 + (l & 31)) << 10;

    // B frags: ct = wv*4 + n; addr(ks,n) = wb + ks*8192 + n*512 (ushorts)
    const ushort* wb = wf + ((size_t)(wv * 4) * 64 + l) * 8;

    f32x16 acc[2][4];
#pragma unroll
    for (int m = 0; m < 2; ++m)
#pragma unroll
        for (int n = 0; n < 4; ++n)
#pragma unroll
            for (int r = 0; r < 16; ++r) acc[m][n][r] = 0.f;

    short8 bq0[4], bq1[4];
#pragma unroll
    for (int n = 0; n < 4; ++n) {
        bq0[n] = *(const short8*)(wb + 0 * 8192 + n * 512);
        bq1[n] = *(const short8*)(wb + 1 * 8192 + n * 512);
    }

#define KSTEP(KS, BQ)                                                                  \
    {                                                                                  \
        short8 af[2];                                                                  \
        _Pragma("unroll")                                                              \
        for (int m = 0; m < 2; ++m)                                                    \
            af[m] = *(const short8*)((const char*)sA + rbase[m] +                      \
                                     ((((KS) * 2 + gsel) ^ rx) << 4));                 \
        _Pragma("unroll")                                                              \
        for (int m = 0; m < 2; ++m)                                                    \
            _Pragma("unroll")                                                          \
            for (int n = 0; n < 4; ++n)                                                \
                acc[m][n] = __builtin_amdgcn_mfma_f32_32x32x16_bf16(af[m], BQ[n],      \
                                                                   acc[m][n], 0, 0, 0);\
        if ((KS) < 30) {                                                               \
            _Pragma("unroll")                                                          \
            for (int n = 0; n < 4; ++n)                                                \
                BQ[n] = *(const short8*)(wb + (size_t)((KS) + 2) * 8192 + n * 512);    \
        }                                                                              \
    }

#pragma unroll
    for (int kp = 0; kp < 16; ++kp) {
        KSTEP(2 * kp, bq0);
        KSTEP(2 * kp + 1, bq1);
    }
#undef KSTEP

    // ---------- epilogue: per-row num = sum_c P*img[c], den = sum_c P^2 ----------
    float ic[4];
#pragma unroll
    for (int n = 0; n < 4; ++n)
        ic[n] = img[b * D_EMB + wv * 128 + n * 32 + (l & 31)];
#pragma unroll
    for (int m = 0; m < 2; ++m) {
#pragma unroll
        for (int rg = 0; rg < 16; ++rg) {
            float tn = 0.f, td = 0.f;
#pragma unroll
            for (int n = 0; n < 4; ++n) {
                const float pv = acc[m][n][rg];
                tn = fmaf(pv, ic[n], tn);
                td = fmaf(pv, pv, td);
            }
#pragma unroll
            for (int off = 1; off <= 16; off <<= 1) {
                tn += __shfl_xor(tn, off);
                td += __shfl_xor(td, off);
            }
            if ((l & 31) == 0) {
                const int r = m * 32 + (rg & 3) + 8 * (rg >> 2) + 4 * (l >> 5);
                redN[wv][r] = tn;
                redD[wv][r] = td;
            }
        }
    }
    __syncthreads();
    if (tid < 64) {
        float tn = 0.f, td = 0.f;
#pragma unroll
        for (int w = 0; w < 4; ++w) { tn += redN[w][tid]; td += redD[w][tid]; }
        numA[row0 + tid] = tn;
        denA[row0 + tid] = td;
    }
}

// ---------------- logits + full bitonic sort + output assembly ----------------
__global__ __launch_bounds__(512) void k_topk(const float* __restrict__ numA,
                                              const float* __restrict__ denA,
                                              const float* __restrict__ logit_in,
                                              const float* __restrict__ p_ls,
                                              float* __restrict__ out) {
    const int b = blockIdx.x;
    const int tid = threadIdx.x;
    const float scale = expf(p_ls[0]);
    __shared__ float a[N_OTH];
    for (int i = tid; i < N_OTH; i += 512) {
        const size_t idx = (size_t)b * N_OTH + i;
        a[i] = scale * numA[idx] / sqrtf(denA[idx]);
    }
    __syncthreads();
    for (unsigned k = 2; k <= N_OTH; k <<= 1) {
        for (unsigned j = k >> 1; j > 0; j >>= 1) {
#pragma unroll
            for (int s = 0; s < N_OTH / 512; ++s) {
                const unsigned i = tid + s * 512u;
                const unsigned ixj = i ^ j;
                if (ixj > i) {
                    const bool asc = ((i & k) == 0);
                    const float x = a[i], y = a[ixj];
                    if ((x > y) == asc) { a[i] = y; a[ixj] = x; }
                }
            }
            __syncthreads();
        }
    }
    if (tid < 128) {
        const int j = tid;
        float v;
        if (j == b) {
            v = logit_in[b];
        } else {
            const int m = j - (j > b ? 1 : 0);
            v = a[N_OTH - 1 - m];
        }
        out[b * 128 + j] = v;
    }
}

extern "C" void kernel_launch(void* const* d_in, const int* in_sizes, int n_in,
                              void* d_out, int out_size, void* d_ws, size_t ws_size,
                              hipStream_t stream) {
    const float* in_img = (const float*)d_in[0];
    const float* in_txt = (const float*)d_in[1];
    const float* oth    = (const float*)d_in[2];
    const float* W_img  = (const float*)d_in[3];
    const float* W_txt  = (const float*)d_in[4];
    const float* p_ls   = (const float*)d_in[5];
    float* out = (float*)d_out;

    float* ws = (float*)d_ws;
    float* img      = ws;                                   // 65536
    float* logit_in = ws + 65536;                           // 128
    float* numA     = ws + 65536 + 128;                     // TOT
    float* denA     = numA + TOT;                           // TOT
    ushort* wfrag   = (ushort*)(denA + TOT);                // 262144 ushorts

    k_prep<<<B_SZ + 64, 512, 0, stream>>>(in_img, in_txt, W_img, W_txt, p_ls, img, logit_in, wfrag);
    k_gemm<<<TOT / 64, 256, 0, stream>>>(oth, wfrag, img, numA, denA);
    k_topk<<<B_SZ, 512, 0, stream>>>(numA, denA, logit_in, p_ls, out);
}